// Round 9
// baseline (252.253 us; speedup 1.0000x reference)
//
#include <hip/hip_runtime.h>
#include <hip/hip_cooperative_groups.h>
#include <math.h>

namespace cg = cooperative_groups;

#define IMG_H 448
#define IMG_W 800
#define GRIDN 224
#define NCAM 6
#define NBOX 48
#define NPAIR (NCAM * NBOX)
#define NCLASS 10
#define FEATD 768
#define POOLD 588
#define PROWS 14
#define KSPLIT 4
#define KCH 147  // 588 / 4
#define BS 256

// ws layout (floats):
//  WS_PAIR  [0, 288*4)         per-pair {x1, y1, sq, vis}
//  WS_POOL  288*588            pooled features per pair
//  WS_FEAT  288*4*768          partial feature sums (K-split)
//  WS_PROBS 288*10             per-pair softmax probs
#define WS_PAIR 0
#define WS_POOL (NPAIR * 4)
#define WS_FEAT (WS_POOL + NPAIR * POOLD)
#define WS_PROBS (WS_FEAT + NPAIR * KSPLIT * FEATD)

__global__ void __launch_bounds__(BS, 4) fused_kernel(
    const float* __restrict__ imgs, const float* __restrict__ boxes7,
    const float* __restrict__ l2i, const float* __restrict__ img_aug,
    const float* __restrict__ lidar_aug, const float* __restrict__ W,
    const float* __restrict__ text, const float* __restrict__ ls_ptr,
    const int* __restrict__ gt, float* __restrict__ ws, float* __restrict__ out) {
    cg::grid_group grid = cg::this_grid();
    int tid = threadIdx.x;
    int bid = blockIdx.x;
    int nblk = gridDim.x;

    __shared__ float s_pw[4];    // x1, y1, sq, vis
    __shared__ float s_pk[KCH];  // pooled K-chunk for head phase
    __shared__ float rn[4];
    __shared__ float rl[4][NCLASS];
    __shared__ float rq[4][NCLASS];

    // ===== Phase B: bbox (lanes 0..7) + bilinear sample + 16x16 pool =====
    for (int tile = bid; tile < NPAIR * PROWS; tile += nblk) {
        int pair = tile / PROWS, pr = tile % PROWS;
        int cam = pair / NBOX, box = pair % NBOX;
        if (tid < 8) {
            int k = tid;  // corner index
            // inverse of lidar_aug[:3,:3] (general; identity in practice)
            float R[9];
            for (int i = 0; i < 3; ++i)
                for (int j = 0; j < 3; ++j) R[i * 3 + j] = lidar_aug[i * 4 + j];
            float ltx = lidar_aug[3], lty = lidar_aug[7], ltz = lidar_aug[11];
            float det = R[0] * (R[4] * R[8] - R[5] * R[7]) -
                        R[1] * (R[3] * R[8] - R[5] * R[6]) +
                        R[2] * (R[3] * R[7] - R[4] * R[6]);
            float i0 = (R[4] * R[8] - R[5] * R[7]) / det;
            float i1 = (R[2] * R[7] - R[1] * R[8]) / det;
            float i2 = (R[1] * R[5] - R[2] * R[4]) / det;
            float i3 = (R[5] * R[6] - R[3] * R[8]) / det;
            float i4 = (R[0] * R[8] - R[2] * R[6]) / det;
            float i5 = (R[2] * R[3] - R[0] * R[5]) / det;
            float i6 = (R[3] * R[7] - R[4] * R[6]) / det;
            float i7 = (R[1] * R[6] - R[0] * R[7]) / det;
            float i8 = (R[0] * R[4] - R[1] * R[3]) / det;

            const float* M = l2i + cam * 16;
            const float* A = img_aug + cam * 16;
            const float* bxp = boxes7 + box * 7;
            float cx = bxp[0], cy = bxp[1], cz = bxp[2];
            float dx = bxp[3], dy = bxp[4], dz = bxp[5], hd = bxp[6];
            float ch = cosf(hd), sh = sinf(hd);
            // corner template: x: +,+,-,-  y: +,-,-,+  z: k<4 ? - : +
            float tx = (k & 2) ? -0.5f : 0.5f;
            float ty = ((k + 1) & 2) ? -0.5f : 0.5f;
            float tz = (k & 4) ? 0.5f : -0.5f;
            float lx = dx * tx, ly = dy * ty, lz = dz * tz;
            float wx = lx * ch - ly * sh + cx;
            float wy = lx * sh + ly * ch + cy;
            float wz = lz + cz;
            float px_ = wx - ltx, py_ = wy - lty, pz_ = wz - ltz;
            float qx = i0 * px_ + i1 * py_ + i2 * pz_;
            float qy = i3 * px_ + i4 * py_ + i5 * pz_;
            float qz = i6 * px_ + i7 * py_ + i8 * pz_;
            float p0 = M[0] * qx + M[1] * qy + M[2] * qz + M[3];
            float p1 = M[4] * qx + M[5] * qy + M[6] * qz + M[7];
            float p2 = M[8] * qx + M[9] * qy + M[10] * qz + M[11];
            float zc = fminf(fmaxf(p2, 1e-5f), 1e5f);
            float sx = p0 / zc, sy = p1 / zc;
            float q0 = A[0] * sx + A[1] * sy + A[2] * zc + A[3];
            float q1 = A[4] * sx + A[5] * sy + A[6] * zc + A[7];
            float row = q1, col = q0;
            int on = (row < (float)IMG_H) && (row >= 0.f) && (col < (float)IMG_W) &&
                     (col >= 0.f);
            int ri = (int)row;  // trunc toward zero (matches jnp.trunc->int32)
            int ci = (int)col;
            int minr = ri, maxr = ri, minc = ci, maxc = ci, visv = on;
            for (int off = 4; off >= 1; off >>= 1) {
                minr = min(minr, __shfl_xor(minr, off, 8));
                maxr = max(maxr, __shfl_xor(maxr, off, 8));
                minc = min(minc, __shfl_xor(minc, off, 8));
                maxc = max(maxc, __shfl_xor(maxc, off, 8));
                visv |= __shfl_xor(visv, off, 8);
            }
            if (tid == 0) {
                int x1 = min(max(minc, 0), IMG_W);
                int x2 = min(max(maxc, 0), IMG_W);
                int y1 = min(max(minr, 0), IMG_H);
                int y2 = min(max(maxr, 0), IMG_H);
                float sq = fmaxf((float)max(x2 - x1, y2 - y1), 64.0f);
                s_pw[0] = (float)x1;
                s_pw[1] = (float)y1;
                s_pw[2] = sq;
                s_pw[3] = visv ? 1.0f : 0.0f;
                if (pr == 0) {
                    float* pw = ws + WS_PAIR + pair * 4;
                    pw[0] = (float)x1; pw[1] = (float)y1; pw[2] = sq;
                    pw[3] = visv ? 1.0f : 0.0f;
                }
            }
        }
        __syncthreads();
        bool vis = s_pw[3] != 0.f;
        float bx1 = s_pw[0], by1 = s_pw[1], sq = s_pw[2];
        __syncthreads();  // s_pw safe for next loop iteration
        if (!vis) continue;

        const float* img = imgs + (size_t)cam * 3 * IMG_H * IMG_W;
        bool active = tid < GRIDN;
        const float ustep = 1.0f / 223.0f;
        float wx0 = 0.f, wx1 = 0.f, mx0 = 0.f, mx1 = 0.f;
        int xi0 = 0, xi1 = 0;
        if (active) {
            float u = (float)tid * ustep;
            float px = bx1 + sq * u;
            float gx = px / (float)IMG_W * 2.0f - 1.0f;
            float ix = ((gx + 1.0f) * (float)IMG_W - 1.0f) / 2.0f;
            float x0f = floorf(ix);
            wx1 = ix - x0f;
            wx0 = 1.0f - wx1;
            float x1f = x0f + 1.0f;
            mx0 = (x0f >= 0.f && x0f <= (float)(IMG_W - 1)) ? 1.f : 0.f;
            mx1 = (x1f >= 0.f && x1f <= (float)(IMG_W - 1)) ? 1.f : 0.f;
            xi0 = min(max((int)x0f, 0), IMG_W - 1);
            xi1 = min(max((int)x1f, 0), IMG_W - 1);
        }
        float acc0 = 0.f, acc1 = 0.f, acc2 = 0.f;
        for (int r = 0; r < 16; ++r) {
            int i = pr * 16 + r;
            float u = (float)i * ustep;
            float py = by1 + sq * u;
            float gy = py / (float)IMG_H * 2.0f - 1.0f;
            float iy = ((gy + 1.0f) * (float)IMG_H - 1.0f) / 2.0f;
            float y0f = floorf(iy);
            float wy1 = iy - y0f;
            float wy0 = 1.0f - wy1;
            float y1f = y0f + 1.0f;
            float my0 = (y0f >= 0.f && y0f <= (float)(IMG_H - 1)) ? 1.f : 0.f;
            float my1 = (y1f >= 0.f && y1f <= (float)(IMG_H - 1)) ? 1.f : 0.f;
            int yi0 = min(max((int)y0f, 0), IMG_H - 1);
            int yi1 = min(max((int)y1f, 0), IMG_H - 1);
            if (active) {
                int r0 = yi0 * IMG_W, r1 = yi1 * IMG_W;
                float w00 = wx0 * wy0, w10 = wx1 * wy0, w01 = wx0 * wy1, w11 = wx1 * wy1;
                float m00 = mx0 * my0, m10 = mx1 * my0, m01 = mx0 * my1, m11 = mx1 * my1;
                {
                    const float* ip = img;
                    acc0 += ip[r0 + xi0] * m00 * w00 + ip[r0 + xi1] * m10 * w10 +
                            ip[r1 + xi0] * m01 * w01 + ip[r1 + xi1] * m11 * w11;
                }
                {
                    const float* ip = img + (size_t)(IMG_H * IMG_W);
                    acc1 += ip[r0 + xi0] * m00 * w00 + ip[r0 + xi1] * m10 * w10 +
                            ip[r1 + xi0] * m01 * w01 + ip[r1 + xi1] * m11 * w11;
                }
                {
                    const float* ip = img + (size_t)(2 * IMG_H * IMG_W);
                    acc2 += ip[r0 + xi0] * m00 * w00 + ip[r0 + xi1] * m10 * w10 +
                            ip[r1 + xi0] * m01 * w01 + ip[r1 + xi1] * m11 * w11;
                }
            }
        }
        for (int off = 8; off >= 1; off >>= 1) {
            acc0 += __shfl_xor(acc0, off, 16);
            acc1 += __shfl_xor(acc1, off, 16);
            acc2 += __shfl_xor(acc2, off, 16);
        }
        if (active && (tid & 15) == 0) {
            int pj = tid >> 4;
            float* pool = ws + WS_POOL + (size_t)pair * POOLD;
            pool[0 * 196 + pr * 14 + pj] = acc0 * (1.0f / 256.0f);
            pool[1 * 196 + pr * 14 + pj] = acc1 * (1.0f / 256.0f);
            pool[2 * 196 + pr * 14 + pj] = acc2 * (1.0f / 256.0f);
        }
    }

    grid.sync();

    // ===== Phase C: partial GEMV (pair, K-chunk); 256 thr x 3 outputs =====
    for (int task = bid; task < NPAIR * KSPLIT; task += nblk) {
        int pair = task >> 2, kc = task & 3;
        bool vis = ws[WS_PAIR + pair * 4 + 3] != 0.f;
        if (vis) {
            if (tid < KCH) s_pk[tid] = ws[WS_POOL + (size_t)pair * POOLD + kc * KCH + tid];
            __syncthreads();
            const float* Wp = W + (size_t)(kc * KCH) * FEATD;
            float f0 = 0.f, f1 = 0.f, f2 = 0.f;
#pragma unroll 7
            for (int k = 0; k < KCH; ++k) {
                float p = s_pk[k];
                const float* wr = Wp + (size_t)k * FEATD;
                f0 += p * wr[tid];
                f1 += p * wr[tid + 256];
                f2 += p * wr[tid + 512];
            }
            float* fo = ws + WS_FEAT + ((size_t)pair * KSPLIT + kc) * FEATD;
            fo[tid] = f0;
            fo[tid + 256] = f1;
            fo[tid + 512] = f2;
        }
        __syncthreads();  // s_pk safe for next iteration
    }

    grid.sync();

    // ===== Phase D: reduce K-partials, normalize, logits, softmax =====
    for (int pair = bid; pair < NPAIR; pair += nblk) {
        bool vis = ws[WS_PAIR + pair * 4 + 3] != 0.f;
        if (!vis) {
            if (tid < NCLASS) ws[WS_PROBS + pair * NCLASS + tid] = 0.f;
        } else {
            const float* fb = ws + WS_FEAT + (size_t)pair * KSPLIT * FEATD;
            float f0 = 0.f, f1 = 0.f, f2 = 0.f;
            for (int kc = 0; kc < KSPLIT; ++kc) {
                const float* fp = fb + (size_t)kc * FEATD;
                f0 += fp[tid];
                f1 += fp[tid + 256];
                f2 += fp[tid + 512];
            }
            float pn = f0 * f0 + f1 * f1 + f2 * f2;
            float pl[NCLASS], tq[NCLASS];
            for (int k = 0; k < NCLASS; ++k) {
                const float* tr = text + (size_t)k * FEATD;
                float t0 = tr[tid], t1 = tr[tid + 256], t2 = tr[tid + 512];
                pl[k] = f0 * t0 + f1 * t1 + f2 * t2;
                tq[k] = t0 * t0 + t1 * t1 + t2 * t2;
            }
            for (int off = 32; off >= 1; off >>= 1) {
                pn += __shfl_xor(pn, off);
                for (int k = 0; k < NCLASS; ++k) {
                    pl[k] += __shfl_xor(pl[k], off);
                    tq[k] += __shfl_xor(tq[k], off);
                }
            }
            int wave = tid >> 6, lane = tid & 63;
            if (lane == 0) {
                rn[wave] = pn;
                for (int k = 0; k < NCLASS; ++k) {
                    rl[wave][k] = pl[k];
                    rq[wave][k] = tq[k];
                }
            }
            __syncthreads();
            if (tid == 0) {
                float n2 = rn[0] + rn[1] + rn[2] + rn[3];
                float nrm = sqrtf(n2);
                float scale = expf(ls_ptr[0]);
                float lg[NCLASS], m = -1e30f;
                for (int k = 0; k < NCLASS; ++k) {
                    float d = rl[0][k] + rl[1][k] + rl[2][k] + rl[3][k];
                    float tn = sqrtf(rq[0][k] + rq[1][k] + rq[2][k] + rq[3][k]);
                    lg[k] = scale * (d / (nrm * tn));
                    m = fmaxf(m, lg[k]);
                }
                float s = 0.f;
                for (int k = 0; k < NCLASS; ++k) {
                    lg[k] = expf(lg[k] - m);
                    s += lg[k];
                }
                float* probs = ws + WS_PROBS + pair * NCLASS;
                for (int k = 0; k < NCLASS; ++k) probs[k] = lg[k] / s;
            }
            __syncthreads();  // rn/rl/rq safe for next iteration
        }
    }

    grid.sync();

    // ===== Phase E: per-box camera mean, argmax, accuracy, outputs =====
    if (bid == 0 && tid < 64) {
        int n = tid;
        bool match = false;
        if (n < NBOX) {
            const float* probs = ws + WS_PROBS;
            float cnt = 0.f;
            for (int c = 0; c < NCAM; ++c)
                cnt += (ws[WS_PAIR + (c * NBOX + n) * 4 + 3] != 0.f) ? 1.f : 0.f;
            float denom = fmaxf(cnt, 1.0f);
            float mp[NCLASS];
            for (int k = 0; k < NCLASS; ++k) {
                float s = 0.f;
                for (int c = 0; c < NCAM; ++c) s += probs[(c * NBOX + n) * NCLASS + k];
                mp[k] = s / denom;
                out[97 + n * NCLASS + k] = mp[k];
            }
            float best = mp[0];
            int pred = 0;
            for (int k = 1; k < NCLASS; ++k)
                if (mp[k] > best) { best = mp[k]; pred = k; }
            int tr = gt[n] - 1;
            out[n] = (float)pred;
            out[NBOX + n] = (float)tr;
            match = (pred == tr);
        }
        unsigned long long b = __ballot(match);
        if (n == 0) out[2 * NBOX] = (float)__popcll(b) / (float)NBOX;
    }
}

extern "C" void kernel_launch(void* const* d_in, const int* in_sizes, int n_in,
                              void* d_out, int out_size, void* d_ws, size_t ws_size,
                              hipStream_t stream) {
    const float* boxes7 = (const float*)d_in[0];
    const int* gt = (const int*)d_in[1];
    const float* imgs = (const float*)d_in[2];
    const float* l2i = (const float*)d_in[3];
    const float* img_aug = (const float*)d_in[4];
    const float* lidar_aug = (const float*)d_in[5];
    const float* W = (const float*)d_in[6];
    const float* text = (const float*)d_in[7];
    const float* ls = (const float*)d_in[8];
    float* ws = (float*)d_ws;
    float* out = (float*)d_out;

    // co-residency-safe grid size for the cooperative launch
    int maxBlocksPerCU = 0;
    hipOccupancyMaxActiveBlocksPerMultiprocessor(&maxBlocksPerCU, fused_kernel, BS, 0);
    if (maxBlocksPerCU < 1) maxBlocksPerCU = 1;
    int nblk = maxBlocksPerCU * 256;  // 256 CUs on MI355X
    if (nblk > 1024) nblk = 1024;

    void* kargs[] = {(void*)&imgs,     (void*)&boxes7, (void*)&l2i, (void*)&img_aug,
                     (void*)&lidar_aug, (void*)&W,      (void*)&text, (void*)&ls,
                     (void*)&gt,        (void*)&ws,     (void*)&out};
    hipLaunchCooperativeKernel(fused_kernel, dim3(nblk), dim3(BS), kargs, 0, stream);
}

// Round 10
// 49.698 us; speedup vs baseline: 5.0758x; 5.0758x over previous
//
#include <hip/hip_runtime.h>
#include <math.h>

#define IMG_H 448
#define IMG_W 800
#define GRIDN 224
#define NCAM 6
#define NBOX 48
#define NPAIR (NCAM * NBOX)
#define NCLASS 10
#define FEATD 768
#define POOLD 588
#define PROWS 14
#define KSPLIT 4
#define KCH 147  // 588 / 4

// ws layout (floats):
//  WS_PAIR  [0, 288*4)         per-pair {x1, y1, sq, vis}
//  WS_POOL  288*588            pooled features per pair
//  WS_FEAT  288*4*768          partial feature sums (K-split)
//  WS_PROBS 288*10             per-pair softmax probs
#define WS_PAIR 0
#define WS_POOL (NPAIR * 4)
#define WS_FEAT (WS_POOL + NPAIR * POOLD)
#define WS_PROBS (WS_FEAT + NPAIR * KSPLIT * FEATD)

// One block per (pair, pooled-row). 256 threads; thread = grid column (224 active).
// Lanes 0-7 compute the pair bbox inline (corner projection + 8-lane reduce);
// the pr==0 block publishes {x1,y1,sq,vis} to ws for the head/finalize kernels.
__global__ void __launch_bounds__(256) pool_kernel(const float* __restrict__ imgs,
                                                   const float* __restrict__ boxes7,
                                                   const float* __restrict__ l2i,
                                                   const float* __restrict__ img_aug,
                                                   const float* __restrict__ lidar_aug,
                                                   float* __restrict__ ws) {
    int pair = blockIdx.x / PROWS;
    int pr = blockIdx.x % PROWS;
    int cam = pair / NBOX, box = pair % NBOX;
    int tid = threadIdx.x;

    __shared__ float s_pw[4];  // x1, y1, sq, vis

    if (tid < 8) {
        int k = tid;  // corner index
        // inverse of lidar_aug[:3,:3] (general; identity in practice)
        float R[9];
        for (int i = 0; i < 3; ++i)
            for (int j = 0; j < 3; ++j) R[i * 3 + j] = lidar_aug[i * 4 + j];
        float ltx = lidar_aug[3], lty = lidar_aug[7], ltz = lidar_aug[11];
        float det = R[0] * (R[4] * R[8] - R[5] * R[7]) - R[1] * (R[3] * R[8] - R[5] * R[6]) +
                    R[2] * (R[3] * R[7] - R[4] * R[6]);
        float i0 = (R[4] * R[8] - R[5] * R[7]) / det;
        float i1 = (R[2] * R[7] - R[1] * R[8]) / det;
        float i2 = (R[1] * R[5] - R[2] * R[4]) / det;
        float i3 = (R[5] * R[6] - R[3] * R[8]) / det;
        float i4 = (R[0] * R[8] - R[2] * R[6]) / det;
        float i5 = (R[2] * R[3] - R[0] * R[5]) / det;
        float i6 = (R[3] * R[7] - R[4] * R[6]) / det;
        float i7 = (R[1] * R[6] - R[0] * R[7]) / det;
        float i8 = (R[0] * R[4] - R[1] * R[3]) / det;

        const float* M = l2i + cam * 16;
        const float* A = img_aug + cam * 16;
        const float* bxp = boxes7 + box * 7;
        float cx = bxp[0], cy = bxp[1], cz = bxp[2];
        float dx = bxp[3], dy = bxp[4], dz = bxp[5], hd = bxp[6];
        float ch = cosf(hd), sh = sinf(hd);
        // corner template: x: +,+,-,-  y: +,-,-,+  z: k<4 ? - : +
        float tx = (k & 2) ? -0.5f : 0.5f;
        float ty = ((k + 1) & 2) ? -0.5f : 0.5f;
        float tz = (k & 4) ? 0.5f : -0.5f;
        float lx = dx * tx, ly = dy * ty, lz = dz * tz;
        float wx = lx * ch - ly * sh + cx;
        float wy = lx * sh + ly * ch + cy;
        float wz = lz + cz;
        float px_ = wx - ltx, py_ = wy - lty, pz_ = wz - ltz;
        float qx = i0 * px_ + i1 * py_ + i2 * pz_;
        float qy = i3 * px_ + i4 * py_ + i5 * pz_;
        float qz = i6 * px_ + i7 * py_ + i8 * pz_;
        float p0 = M[0] * qx + M[1] * qy + M[2] * qz + M[3];
        float p1 = M[4] * qx + M[5] * qy + M[6] * qz + M[7];
        float p2 = M[8] * qx + M[9] * qy + M[10] * qz + M[11];
        float zc = fminf(fmaxf(p2, 1e-5f), 1e5f);
        float sx = p0 / zc, sy = p1 / zc;
        float q0 = A[0] * sx + A[1] * sy + A[2] * zc + A[3];
        float q1 = A[4] * sx + A[5] * sy + A[6] * zc + A[7];
        float row = q1, col = q0;
        int on = (row < (float)IMG_H) && (row >= 0.f) && (col < (float)IMG_W) && (col >= 0.f);
        int ri = (int)row;  // trunc toward zero (matches jnp.trunc->int32)
        int ci = (int)col;
        int minr = ri, maxr = ri, minc = ci, maxc = ci, visv = on;
        for (int off = 4; off >= 1; off >>= 1) {
            minr = min(minr, __shfl_xor(minr, off, 8));
            maxr = max(maxr, __shfl_xor(maxr, off, 8));
            minc = min(minc, __shfl_xor(minc, off, 8));
            maxc = max(maxc, __shfl_xor(maxc, off, 8));
            visv |= __shfl_xor(visv, off, 8);
        }
        if (tid == 0) {
            int x1 = min(max(minc, 0), IMG_W);
            int x2 = min(max(maxc, 0), IMG_W);
            int y1 = min(max(minr, 0), IMG_H);
            int y2 = min(max(maxr, 0), IMG_H);
            float sq = fmaxf((float)max(x2 - x1, y2 - y1), 64.0f);
            s_pw[0] = (float)x1;
            s_pw[1] = (float)y1;
            s_pw[2] = sq;
            s_pw[3] = visv ? 1.0f : 0.0f;
            if (pr == 0) {
                float* pw = ws + WS_PAIR + pair * 4;
                pw[0] = (float)x1; pw[1] = (float)y1; pw[2] = sq;
                pw[3] = visv ? 1.0f : 0.0f;
            }
        }
    }
    __syncthreads();
    if (s_pw[3] == 0.f) return;  // invisible: pooled never consumed
    float bx1 = s_pw[0], by1 = s_pw[1], sq = s_pw[2];

    const float* img = imgs + (size_t)cam * 3 * IMG_H * IMG_W;
    bool active = tid < GRIDN;

    const float ustep = 1.0f / 223.0f;
    float wx0 = 0.f, wx1 = 0.f, mx0 = 0.f, mx1 = 0.f;
    int xi0 = 0, xi1 = 0;
    if (active) {
        float u = (float)tid * ustep;
        float px = bx1 + sq * u;
        float gx = px / (float)IMG_W * 2.0f - 1.0f;
        float ix = ((gx + 1.0f) * (float)IMG_W - 1.0f) / 2.0f;
        float x0f = floorf(ix);
        wx1 = ix - x0f;
        wx0 = 1.0f - wx1;
        float x1f = x0f + 1.0f;
        mx0 = (x0f >= 0.f && x0f <= (float)(IMG_W - 1)) ? 1.f : 0.f;
        mx1 = (x1f >= 0.f && x1f <= (float)(IMG_W - 1)) ? 1.f : 0.f;
        xi0 = min(max((int)x0f, 0), IMG_W - 1);
        xi1 = min(max((int)x1f, 0), IMG_W - 1);
    }
    float acc0 = 0.f, acc1 = 0.f, acc2 = 0.f;
    for (int r = 0; r < 16; ++r) {
        int i = pr * 16 + r;
        float u = (float)i * ustep;
        float py = by1 + sq * u;
        float gy = py / (float)IMG_H * 2.0f - 1.0f;
        float iy = ((gy + 1.0f) * (float)IMG_H - 1.0f) / 2.0f;
        float y0f = floorf(iy);
        float wy1 = iy - y0f;
        float wy0 = 1.0f - wy1;
        float y1f = y0f + 1.0f;
        float my0 = (y0f >= 0.f && y0f <= (float)(IMG_H - 1)) ? 1.f : 0.f;
        float my1 = (y1f >= 0.f && y1f <= (float)(IMG_H - 1)) ? 1.f : 0.f;
        int yi0 = min(max((int)y0f, 0), IMG_H - 1);
        int yi1 = min(max((int)y1f, 0), IMG_H - 1);
        if (active) {
            int r0 = yi0 * IMG_W, r1 = yi1 * IMG_W;
            float w00 = wx0 * wy0, w10 = wx1 * wy0, w01 = wx0 * wy1, w11 = wx1 * wy1;
            float m00 = mx0 * my0, m10 = mx1 * my0, m01 = mx0 * my1, m11 = mx1 * my1;
            {
                const float* ip = img;
                acc0 += ip[r0 + xi0] * m00 * w00 + ip[r0 + xi1] * m10 * w10 +
                        ip[r1 + xi0] * m01 * w01 + ip[r1 + xi1] * m11 * w11;
            }
            {
                const float* ip = img + (size_t)(IMG_H * IMG_W);
                acc1 += ip[r0 + xi0] * m00 * w00 + ip[r0 + xi1] * m10 * w10 +
                        ip[r1 + xi0] * m01 * w01 + ip[r1 + xi1] * m11 * w11;
            }
            {
                const float* ip = img + (size_t)(2 * IMG_H * IMG_W);
                acc2 += ip[r0 + xi0] * m00 * w00 + ip[r0 + xi1] * m10 * w10 +
                        ip[r1 + xi0] * m01 * w01 + ip[r1 + xi1] * m11 * w11;
            }
        }
    }
    // reduce 16 grid-columns -> one pooled cell
    for (int off = 8; off >= 1; off >>= 1) {
        acc0 += __shfl_xor(acc0, off, 16);
        acc1 += __shfl_xor(acc1, off, 16);
        acc2 += __shfl_xor(acc2, off, 16);
    }
    if (active && (tid & 15) == 0) {
        int pj = tid >> 4;
        float* pool = ws + WS_POOL + (size_t)pair * POOLD;
        pool[0 * 196 + pr * 14 + pj] = acc0 * (1.0f / 256.0f);
        pool[1 * 196 + pr * 14 + pj] = acc1 * (1.0f / 256.0f);
        pool[2 * 196 + pr * 14 + pj] = acc2 * (1.0f / 256.0f);
    }
}

// Partial GEMV: one block per (pair, K-chunk); 768 threads, thread = output dim.
__global__ void __launch_bounds__(768) head1_kernel(const float* __restrict__ W,
                                                    float* __restrict__ ws) {
    int pair = blockIdx.x / KSPLIT;
    int kc = blockIdx.x % KSPLIT;
    if (ws[WS_PAIR + pair * 4 + 3] == 0.f) return;  // invisible: partials unused
    int tid = threadIdx.x;
    __shared__ float pk[KCH];
    if (tid < KCH) pk[tid] = ws[WS_POOL + (size_t)pair * POOLD + kc * KCH + tid];
    __syncthreads();
    const float* Wp = W + (size_t)(kc * KCH) * FEATD + tid;
    float f = 0.f;
#pragma unroll 7
    for (int k = 0; k < KCH; ++k) f += pk[k] * Wp[(size_t)k * FEATD];
    ws[WS_FEAT + ((size_t)pair * KSPLIT + kc) * FEATD + tid] = f;
}

// Reduce K-partials, normalize, logits vs text (norms computed in-block), softmax.
__global__ void __launch_bounds__(256) head2_kernel(const float* __restrict__ text,
                                                    const float* __restrict__ ls_ptr,
                                                    float* __restrict__ ws) {
    int pair = blockIdx.x;
    int tid = threadIdx.x;
    const float* pw = ws + WS_PAIR + pair * 4;
    if (pw[3] == 0.f) {  // invisible: probs = 0 (masked in reference)
        if (tid < NCLASS) ws[WS_PROBS + pair * NCLASS + tid] = 0.f;
        return;
    }
    const float* fb = ws + WS_FEAT + (size_t)pair * KSPLIT * FEATD;
    float f0 = 0.f, f1 = 0.f, f2 = 0.f;
    for (int kc = 0; kc < KSPLIT; ++kc) {
        const float* fp = fb + (size_t)kc * FEATD;
        f0 += fp[tid];
        f1 += fp[tid + 256];
        f2 += fp[tid + 512];
    }
    float pn = f0 * f0 + f1 * f1 + f2 * f2;
    float pl[NCLASS], tq[NCLASS];
    for (int k = 0; k < NCLASS; ++k) {
        const float* tr = text + (size_t)k * FEATD;
        float t0 = tr[tid], t1 = tr[tid + 256], t2 = tr[tid + 512];
        pl[k] = f0 * t0 + f1 * t1 + f2 * t2;
        tq[k] = t0 * t0 + t1 * t1 + t2 * t2;
    }
    for (int off = 32; off >= 1; off >>= 1) {
        pn += __shfl_xor(pn, off);
        for (int k = 0; k < NCLASS; ++k) {
            pl[k] += __shfl_xor(pl[k], off);
            tq[k] += __shfl_xor(tq[k], off);
        }
    }
    __shared__ float rn[4];
    __shared__ float rl[4][NCLASS];
    __shared__ float rq[4][NCLASS];
    int wave = tid >> 6, lane = tid & 63;
    if (lane == 0) {
        rn[wave] = pn;
        for (int k = 0; k < NCLASS; ++k) { rl[wave][k] = pl[k]; rq[wave][k] = tq[k]; }
    }
    __syncthreads();
    if (tid == 0) {
        float n2 = rn[0] + rn[1] + rn[2] + rn[3];
        float nrm = sqrtf(n2);
        float scale = expf(ls_ptr[0]);
        float lg[NCLASS], m = -1e30f;
        for (int k = 0; k < NCLASS; ++k) {
            float d = rl[0][k] + rl[1][k] + rl[2][k] + rl[3][k];
            float tn = sqrtf(rq[0][k] + rq[1][k] + rq[2][k] + rq[3][k]);
            lg[k] = scale * (d / (nrm * tn));
            m = fmaxf(m, lg[k]);
        }
        float s = 0.f;
        for (int k = 0; k < NCLASS; ++k) {
            lg[k] = expf(lg[k] - m);
            s += lg[k];
        }
        float* probs = ws + WS_PROBS + pair * NCLASS;
        for (int k = 0; k < NCLASS; ++k) probs[k] = lg[k] / s;
    }
}

__global__ void finalize_kernel(const int* __restrict__ gt, const float* __restrict__ ws,
                                float* __restrict__ out) {
    int n = threadIdx.x;
    bool match = false;
    if (n < NBOX) {
        const float* probs = ws + WS_PROBS;
        float cnt = 0.f;
        for (int c = 0; c < NCAM; ++c)
            cnt += (ws[WS_PAIR + (c * NBOX + n) * 4 + 3] != 0.f) ? 1.f : 0.f;
        float denom = fmaxf(cnt, 1.0f);
        float mp[NCLASS];
        for (int k = 0; k < NCLASS; ++k) {
            float s = 0.f;
            for (int c = 0; c < NCAM; ++c) s += probs[(c * NBOX + n) * NCLASS + k];
            mp[k] = s / denom;
            out[97 + n * NCLASS + k] = mp[k];
        }
        float best = mp[0];
        int pred = 0;
        for (int k = 1; k < NCLASS; ++k)
            if (mp[k] > best) { best = mp[k]; pred = k; }
        int tr = gt[n] - 1;
        out[n] = (float)pred;
        out[NBOX + n] = (float)tr;
        match = (pred == tr);
    }
    unsigned long long b = __ballot(match);
    if (n == 0) out[2 * NBOX] = (float)__popcll(b) / (float)NBOX;
}

extern "C" void kernel_launch(void* const* d_in, const int* in_sizes, int n_in,
                              void* d_out, int out_size, void* d_ws, size_t ws_size,
                              hipStream_t stream) {
    const float* boxes7 = (const float*)d_in[0];
    const int* gt = (const int*)d_in[1];
    const float* imgs = (const float*)d_in[2];
    const float* l2i = (const float*)d_in[3];
    const float* img_aug = (const float*)d_in[4];
    const float* lidar_aug = (const float*)d_in[5];
    const float* W = (const float*)d_in[6];
    const float* text = (const float*)d_in[7];
    const float* ls = (const float*)d_in[8];
    float* ws = (float*)d_ws;
    float* out = (float*)d_out;

    pool_kernel<<<NPAIR * PROWS, 256, 0, stream>>>(imgs, boxes7, l2i, img_aug, lidar_aug, ws);
    head1_kernel<<<NPAIR * KSPLIT, 768, 0, stream>>>(W, ws);
    head2_kernel<<<NPAIR, 256, 0, stream>>>(text, ls, ws);
    finalize_kernel<<<1, 64, 0, stream>>>(gt, ws, out);
}

// Round 11
// 48.725 us; speedup vs baseline: 5.1770x; 1.0200x over previous
//
#include <hip/hip_runtime.h>
#include <math.h>

#define IMG_H 448
#define IMG_W 800
#define GRIDN 224
#define NCAM 6
#define NBOX 48
#define NPAIR (NCAM * NBOX)
#define NCLASS 10
#define FEATD 768
#define POOLD 588
#define PROWS 14
#define KSPLIT 4
#define KCH 147  // 588 / 4

// ws layout (floats):
//  WS_PAIR  [0, 288*4)         per-pair {x1, y1, sq, vis}
//  WS_POOL  288*588            pooled features per pair
//  WS_FEAT  288*4*768          partial feature sums (K-split)
//  WS_PROBS 288*10             per-pair softmax probs
#define WS_PAIR 0
#define WS_POOL (NPAIR * 4)
#define WS_FEAT (WS_POOL + NPAIR * POOLD)
#define WS_PROBS (WS_FEAT + NPAIR * KSPLIT * FEATD)

// One block per (pair, pooled-row). 256 threads; thread = grid column (224 active).
// Lanes 0-7 compute the pair bbox inline; pr==0 block publishes it to ws.
// The 16 sample rows advance by sq/223 px; (yi0,yi1) are wave-uniform, so the
// two active pixel rows' tap values are cached in registers and reloaded only
// on row change (big gather-instruction saving when sq is near MIN_SIZE=64).
__global__ void __launch_bounds__(256) pool_kernel(const float* __restrict__ imgs,
                                                   const float* __restrict__ boxes7,
                                                   const float* __restrict__ l2i,
                                                   const float* __restrict__ img_aug,
                                                   const float* __restrict__ lidar_aug,
                                                   float* __restrict__ ws) {
    int pair = blockIdx.x / PROWS;
    int pr = blockIdx.x % PROWS;
    int cam = pair / NBOX, box = pair % NBOX;
    int tid = threadIdx.x;

    __shared__ float s_pw[4];  // x1, y1, sq, vis

    if (tid < 8) {
        int k = tid;  // corner index
        float R[9];
        for (int i = 0; i < 3; ++i)
            for (int j = 0; j < 3; ++j) R[i * 3 + j] = lidar_aug[i * 4 + j];
        float ltx = lidar_aug[3], lty = lidar_aug[7], ltz = lidar_aug[11];
        float det = R[0] * (R[4] * R[8] - R[5] * R[7]) - R[1] * (R[3] * R[8] - R[5] * R[6]) +
                    R[2] * (R[3] * R[7] - R[4] * R[6]);
        float i0 = (R[4] * R[8] - R[5] * R[7]) / det;
        float i1 = (R[2] * R[7] - R[1] * R[8]) / det;
        float i2 = (R[1] * R[5] - R[2] * R[4]) / det;
        float i3 = (R[5] * R[6] - R[3] * R[8]) / det;
        float i4 = (R[0] * R[8] - R[2] * R[6]) / det;
        float i5 = (R[2] * R[3] - R[0] * R[5]) / det;
        float i6 = (R[3] * R[7] - R[4] * R[6]) / det;
        float i7 = (R[1] * R[6] - R[0] * R[7]) / det;
        float i8 = (R[0] * R[4] - R[1] * R[3]) / det;

        const float* M = l2i + cam * 16;
        const float* A = img_aug + cam * 16;
        const float* bxp = boxes7 + box * 7;
        float cx = bxp[0], cy = bxp[1], cz = bxp[2];
        float dx = bxp[3], dy = bxp[4], dz = bxp[5], hd = bxp[6];
        float ch = cosf(hd), sh = sinf(hd);
        float tx = (k & 2) ? -0.5f : 0.5f;
        float ty = ((k + 1) & 2) ? -0.5f : 0.5f;
        float tz = (k & 4) ? 0.5f : -0.5f;
        float lx = dx * tx, ly = dy * ty, lz = dz * tz;
        float wx = lx * ch - ly * sh + cx;
        float wy = lx * sh + ly * ch + cy;
        float wz = lz + cz;
        float px_ = wx - ltx, py_ = wy - lty, pz_ = wz - ltz;
        float qx = i0 * px_ + i1 * py_ + i2 * pz_;
        float qy = i3 * px_ + i4 * py_ + i5 * pz_;
        float qz = i6 * px_ + i7 * py_ + i8 * pz_;
        float p0 = M[0] * qx + M[1] * qy + M[2] * qz + M[3];
        float p1 = M[4] * qx + M[5] * qy + M[6] * qz + M[7];
        float p2 = M[8] * qx + M[9] * qy + M[10] * qz + M[11];
        float zc = fminf(fmaxf(p2, 1e-5f), 1e5f);
        float sx = p0 / zc, sy = p1 / zc;
        float q0 = A[0] * sx + A[1] * sy + A[2] * zc + A[3];
        float q1 = A[4] * sx + A[5] * sy + A[6] * zc + A[7];
        float row = q1, col = q0;
        int on = (row < (float)IMG_H) && (row >= 0.f) && (col < (float)IMG_W) && (col >= 0.f);
        int ri = (int)row;  // trunc toward zero (matches jnp.trunc->int32)
        int ci = (int)col;
        int minr = ri, maxr = ri, minc = ci, maxc = ci, visv = on;
        for (int off = 4; off >= 1; off >>= 1) {
            minr = min(minr, __shfl_xor(minr, off, 8));
            maxr = max(maxr, __shfl_xor(maxr, off, 8));
            minc = min(minc, __shfl_xor(minc, off, 8));
            maxc = max(maxc, __shfl_xor(maxc, off, 8));
            visv |= __shfl_xor(visv, off, 8);
        }
        if (tid == 0) {
            int x1 = min(max(minc, 0), IMG_W);
            int x2 = min(max(maxc, 0), IMG_W);
            int y1 = min(max(minr, 0), IMG_H);
            int y2 = min(max(maxr, 0), IMG_H);
            float sq = fmaxf((float)max(x2 - x1, y2 - y1), 64.0f);
            s_pw[0] = (float)x1;
            s_pw[1] = (float)y1;
            s_pw[2] = sq;
            s_pw[3] = visv ? 1.0f : 0.0f;
            if (pr == 0) {
                float* pw = ws + WS_PAIR + pair * 4;
                pw[0] = (float)x1; pw[1] = (float)y1; pw[2] = sq;
                pw[3] = visv ? 1.0f : 0.0f;
            }
        }
    }
    __syncthreads();
    if (s_pw[3] == 0.f) return;  // invisible: pooled never consumed
    float bx1 = s_pw[0], by1 = s_pw[1], sq = s_pw[2];

    const float* img0 = imgs + (size_t)cam * 3 * IMG_H * IMG_W;
    const float* img1 = img0 + (size_t)(IMG_H * IMG_W);
    const float* img2 = img0 + (size_t)(2 * IMG_H * IMG_W);
    bool active = tid < GRIDN;

    const float ustep = 1.0f / 223.0f;
    float wx0 = 0.f, wx1 = 0.f, mx0 = 0.f, mx1 = 0.f;
    int xi0 = 0, xi1 = 0;
    if (active) {
        float u = (float)tid * ustep;
        float px = bx1 + sq * u;
        float gx = px / (float)IMG_W * 2.0f - 1.0f;
        float ix = ((gx + 1.0f) * (float)IMG_W - 1.0f) / 2.0f;
        float x0f = floorf(ix);
        wx1 = ix - x0f;
        wx0 = 1.0f - wx1;
        float x1f = x0f + 1.0f;
        mx0 = (x0f >= 0.f && x0f <= (float)(IMG_W - 1)) ? 1.f : 0.f;
        mx1 = (x1f >= 0.f && x1f <= (float)(IMG_W - 1)) ? 1.f : 0.f;
        xi0 = min(max((int)x0f, 0), IMG_W - 1);
        xi1 = min(max((int)x1f, 0), IMG_W - 1);
    }

    // register-cached tap values for the two active pixel rows (A=yi0, B=yi1)
    int iyA = -0x40000000, iyB = -0x40000000;
    float vA00 = 0.f, vA01 = 0.f, vA10 = 0.f, vA11 = 0.f, vA20 = 0.f, vA21 = 0.f;
    float vB00 = 0.f, vB01 = 0.f, vB10 = 0.f, vB11 = 0.f, vB20 = 0.f, vB21 = 0.f;

    float acc0 = 0.f, acc1 = 0.f, acc2 = 0.f;
    for (int r = 0; r < 16; ++r) {
        int i = pr * 16 + r;
        float u = (float)i * ustep;
        float py = by1 + sq * u;
        float gy = py / (float)IMG_H * 2.0f - 1.0f;
        float iy = ((gy + 1.0f) * (float)IMG_H - 1.0f) / 2.0f;
        float y0f = floorf(iy);
        float wy1 = iy - y0f;
        float wy0 = 1.0f - wy1;
        float y1f = y0f + 1.0f;
        float my0 = (y0f >= 0.f && y0f <= (float)(IMG_H - 1)) ? 1.f : 0.f;
        float my1 = (y1f >= 0.f && y1f <= (float)(IMG_H - 1)) ? 1.f : 0.f;
        int yi0 = min(max((int)y0f, 0), IMG_H - 1);
        int yi1 = min(max((int)y1f, 0), IMG_H - 1);
        // wave-uniform row-cache update (yi0/yi1 identical across the block)
        if (yi0 != iyA || yi1 != iyB) {
            if (yi0 == iyB) {  // common case: rows advanced by one
                vA00 = vB00; vA01 = vB01; vA10 = vB10; vA11 = vB11; vA20 = vB20; vA21 = vB21;
                iyA = iyB;
            } else if (yi0 != iyA) {
                if (active) {
                    int r0 = yi0 * IMG_W;
                    vA00 = img0[r0 + xi0]; vA01 = img0[r0 + xi1];
                    vA10 = img1[r0 + xi0]; vA11 = img1[r0 + xi1];
                    vA20 = img2[r0 + xi0]; vA21 = img2[r0 + xi1];
                }
                iyA = yi0;
            }
            if (yi1 != iyB) {
                if (active) {
                    int r1 = yi1 * IMG_W;
                    vB00 = img0[r1 + xi0]; vB01 = img0[r1 + xi1];
                    vB10 = img1[r1 + xi0]; vB11 = img1[r1 + xi1];
                    vB20 = img2[r1 + xi0]; vB21 = img2[r1 + xi1];
                }
                iyB = yi1;
            }
        }
        if (active) {
            float w00 = wx0 * wy0, w10 = wx1 * wy0, w01 = wx0 * wy1, w11 = wx1 * wy1;
            float m00 = mx0 * my0, m10 = mx1 * my0, m01 = mx0 * my1, m11 = mx1 * my1;
            acc0 += vA00 * m00 * w00 + vA01 * m10 * w10 + vB00 * m01 * w01 + vB01 * m11 * w11;
            acc1 += vA10 * m00 * w00 + vA11 * m10 * w10 + vB10 * m01 * w01 + vB11 * m11 * w11;
            acc2 += vA20 * m00 * w00 + vA21 * m10 * w10 + vB20 * m01 * w01 + vB21 * m11 * w11;
        }
    }
    // reduce 16 grid-columns -> one pooled cell
    for (int off = 8; off >= 1; off >>= 1) {
        acc0 += __shfl_xor(acc0, off, 16);
        acc1 += __shfl_xor(acc1, off, 16);
        acc2 += __shfl_xor(acc2, off, 16);
    }
    if (active && (tid & 15) == 0) {
        int pj = tid >> 4;
        float* pool = ws + WS_POOL + (size_t)pair * POOLD;
        pool[0 * 196 + pr * 14 + pj] = acc0 * (1.0f / 256.0f);
        pool[1 * 196 + pr * 14 + pj] = acc1 * (1.0f / 256.0f);
        pool[2 * 196 + pr * 14 + pj] = acc2 * (1.0f / 256.0f);
    }
}

// Partial GEMV: one block per (pair, K-chunk); 768 threads, thread = output dim.
__global__ void __launch_bounds__(768) head1_kernel(const float* __restrict__ W,
                                                    float* __restrict__ ws) {
    int pair = blockIdx.x / KSPLIT;
    int kc = blockIdx.x % KSPLIT;
    if (ws[WS_PAIR + pair * 4 + 3] == 0.f) return;  // invisible: partials unused
    int tid = threadIdx.x;
    __shared__ float pk[KCH];
    if (tid < KCH) pk[tid] = ws[WS_POOL + (size_t)pair * POOLD + kc * KCH + tid];
    __syncthreads();
    const float* Wp = W + (size_t)(kc * KCH) * FEATD + tid;
    float f = 0.f;
#pragma unroll 7
    for (int k = 0; k < KCH; ++k) f += pk[k] * Wp[(size_t)k * FEATD];
    ws[WS_FEAT + ((size_t)pair * KSPLIT + kc) * FEATD + tid] = f;
}

// Reduce K-partials, normalize, logits vs text (norms computed in-block), softmax.
__global__ void __launch_bounds__(256) head2_kernel(const float* __restrict__ text,
                                                    const float* __restrict__ ls_ptr,
                                                    float* __restrict__ ws) {
    int pair = blockIdx.x;
    int tid = threadIdx.x;
    const float* pw = ws + WS_PAIR + pair * 4;
    if (pw[3] == 0.f) {  // invisible: probs = 0 (masked in reference)
        if (tid < NCLASS) ws[WS_PROBS + pair * NCLASS + tid] = 0.f;
        return;
    }
    const float* fb = ws + WS_FEAT + (size_t)pair * KSPLIT * FEATD;
    float f0 = 0.f, f1 = 0.f, f2 = 0.f;
    for (int kc = 0; kc < KSPLIT; ++kc) {
        const float* fp = fb + (size_t)kc * FEATD;
        f0 += fp[tid];
        f1 += fp[tid + 256];
        f2 += fp[tid + 512];
    }
    float pn = f0 * f0 + f1 * f1 + f2 * f2;
    float pl[NCLASS], tq[NCLASS];
    for (int k = 0; k < NCLASS; ++k) {
        const float* tr = text + (size_t)k * FEATD;
        float t0 = tr[tid], t1 = tr[tid + 256], t2 = tr[tid + 512];
        pl[k] = f0 * t0 + f1 * t1 + f2 * t2;
        tq[k] = t0 * t0 + t1 * t1 + t2 * t2;
    }
    for (int off = 32; off >= 1; off >>= 1) {
        pn += __shfl_xor(pn, off);
        for (int k = 0; k < NCLASS; ++k) {
            pl[k] += __shfl_xor(pl[k], off);
            tq[k] += __shfl_xor(tq[k], off);
        }
    }
    __shared__ float rn[4];
    __shared__ float rl[4][NCLASS];
    __shared__ float rq[4][NCLASS];
    int wave = tid >> 6, lane = tid & 63;
    if (lane == 0) {
        rn[wave] = pn;
        for (int k = 0; k < NCLASS; ++k) { rl[wave][k] = pl[k]; rq[wave][k] = tq[k]; }
    }
    __syncthreads();
    if (tid == 0) {
        float n2 = rn[0] + rn[1] + rn[2] + rn[3];
        float nrm = sqrtf(n2);
        float scale = expf(ls_ptr[0]);
        float lg[NCLASS], m = -1e30f;
        for (int k = 0; k < NCLASS; ++k) {
            float d = rl[0][k] + rl[1][k] + rl[2][k] + rl[3][k];
            float tn = sqrtf(rq[0][k] + rq[1][k] + rq[2][k] + rq[3][k]);
            lg[k] = scale * (d / (nrm * tn));
            m = fmaxf(m, lg[k]);
        }
        float s = 0.f;
        for (int k = 0; k < NCLASS; ++k) {
            lg[k] = expf(lg[k] - m);
            s += lg[k];
        }
        float* probs = ws + WS_PROBS + pair * NCLASS;
        for (int k = 0; k < NCLASS; ++k) probs[k] = lg[k] / s;
    }
}

__global__ void finalize_kernel(const int* __restrict__ gt, const float* __restrict__ ws,
                                float* __restrict__ out) {
    int n = threadIdx.x;
    bool match = false;
    if (n < NBOX) {
        const float* probs = ws + WS_PROBS;
        float cnt = 0.f;
        for (int c = 0; c < NCAM; ++c)
            cnt += (ws[WS_PAIR + (c * NBOX + n) * 4 + 3] != 0.f) ? 1.f : 0.f;
        float denom = fmaxf(cnt, 1.0f);
        float mp[NCLASS];
        for (int k = 0; k < NCLASS; ++k) {
            float s = 0.f;
            for (int c = 0; c < NCAM; ++c) s += probs[(c * NBOX + n) * NCLASS + k];
            mp[k] = s / denom;
            out[97 + n * NCLASS + k] = mp[k];
        }
        float best = mp[0];
        int pred = 0;
        for (int k = 1; k < NCLASS; ++k)
            if (mp[k] > best) { best = mp[k]; pred = k; }
        int tr = gt[n] - 1;
        out[n] = (float)pred;
        out[NBOX + n] = (float)tr;
        match = (pred == tr);
    }
    unsigned long long b = __ballot(match);
    if (n == 0) out[2 * NBOX] = (float)__popcll(b) / (float)NBOX;
}

extern "C" void kernel_launch(void* const* d_in, const int* in_sizes, int n_in,
                              void* d_out, int out_size, void* d_ws, size_t ws_size,
                              hipStream_t stream) {
    const float* boxes7 = (const float*)d_in[0];
    const int* gt = (const int*)d_in[1];
    const float* imgs = (const float*)d_in[2];
    const float* l2i = (const float*)d_in[3];
    const float* img_aug = (const float*)d_in[4];
    const float* lidar_aug = (const float*)d_in[5];
    const float* W = (const float*)d_in[6];
    const float* text = (const float*)d_in[7];
    const float* ls = (const float*)d_in[8];
    float* ws = (float*)d_ws;
    float* out = (float*)d_out;

    pool_kernel<<<NPAIR * PROWS, 256, 0, stream>>>(imgs, boxes7, l2i, img_aug, lidar_aug, ws);
    head1_kernel<<<NPAIR * KSPLIT, 768, 0, stream>>>(W, ws);
    head2_kernel<<<NPAIR, 256, 0, stream>>>(text, ls, ws);
    finalize_kernel<<<1, 64, 0, stream>>>(gt, ws, out);
}

// Round 13
// 44.109 us; speedup vs baseline: 5.7189x; 1.1047x over previous
//
#include <hip/hip_runtime.h>
#include <math.h>

#define IMG_H 448
#define IMG_W 800
#define GRIDN 224
#define NCAM 6
#define NBOX 48
#define NPAIR (NCAM * NBOX)
#define NCLASS 10
#define FEATD 768
#define POOLD 588
#define PROWS 14

// ws layout (floats):
//  WS_PAIR  [0, 288*4)          per-pair {x1, y1, sq, vis}
//  WS_PART  288*14*768          per-(pair,pooled-row) partial feature vectors
//  WS_PROBS 288*10              per-pair softmax probs
#define WS_PAIR 0
#define WS_PART (NPAIR * 4)
#define WS_PROBS (WS_PART + NPAIR * PROWS * FEATD)

// One block per (pair, pooled-row). 256 threads; thread = grid column (224 active).
// Lanes 0-7 compute the pair bbox inline; pr==0 block publishes it to ws.
// After pooling 42 values (3ch x 14 cols) into LDS, the block immediately
// computes their partial GEMV against W (42 rows x 768 dims) and writes a
// per-(pair,pr) partial feature vector -- head1 is fused away.
__global__ void __launch_bounds__(256) pool_gemv_kernel(const float* __restrict__ imgs,
                                                        const float* __restrict__ boxes7,
                                                        const float* __restrict__ l2i,
                                                        const float* __restrict__ img_aug,
                                                        const float* __restrict__ lidar_aug,
                                                        const float* __restrict__ W,
                                                        float* __restrict__ ws) {
    int pair = blockIdx.x / PROWS;
    int pr = blockIdx.x % PROWS;
    int cam = pair / NBOX, box = pair % NBOX;
    int tid = threadIdx.x;

    __shared__ float s_pw[4];        // x1, y1, sq, vis
    __shared__ float s_pool[3 * 14]; // pooled cells for this (pair, pr)

    if (tid < 8) {
        int k = tid;  // corner index
        float R[9];
        for (int i = 0; i < 3; ++i)
            for (int j = 0; j < 3; ++j) R[i * 3 + j] = lidar_aug[i * 4 + j];
        float ltx = lidar_aug[3], lty = lidar_aug[7], ltz = lidar_aug[11];
        float det = R[0] * (R[4] * R[8] - R[5] * R[7]) - R[1] * (R[3] * R[8] - R[5] * R[6]) +
                    R[2] * (R[3] * R[7] - R[4] * R[6]);
        float i0 = (R[4] * R[8] - R[5] * R[7]) / det;
        float i1 = (R[2] * R[7] - R[1] * R[8]) / det;
        float i2 = (R[1] * R[5] - R[2] * R[4]) / det;
        float i3 = (R[5] * R[6] - R[3] * R[8]) / det;
        float i4 = (R[0] * R[8] - R[2] * R[6]) / det;
        float i5 = (R[2] * R[3] - R[0] * R[5]) / det;
        float i6 = (R[3] * R[7] - R[4] * R[6]) / det;
        float i7 = (R[1] * R[6] - R[0] * R[7]) / det;
        float i8 = (R[0] * R[4] - R[1] * R[3]) / det;

        const float* M = l2i + cam * 16;
        const float* A = img_aug + cam * 16;
        const float* bxp = boxes7 + box * 7;
        float cx = bxp[0], cy = bxp[1], cz = bxp[2];
        float dx = bxp[3], dy = bxp[4], dz = bxp[5], hd = bxp[6];
        float ch = cosf(hd), sh = sinf(hd);
        float tx = (k & 2) ? -0.5f : 0.5f;
        float ty = ((k + 1) & 2) ? -0.5f : 0.5f;
        float tz = (k & 4) ? 0.5f : -0.5f;
        float lx = dx * tx, ly = dy * ty, lz = dz * tz;
        float wx = lx * ch - ly * sh + cx;
        float wy = lx * sh + ly * ch + cy;
        float wz = lz + cz;
        float px_ = wx - ltx, py_ = wy - lty, pz_ = wz - ltz;
        float qx = i0 * px_ + i1 * py_ + i2 * pz_;
        float qy = i3 * px_ + i4 * py_ + i5 * pz_;
        float qz = i6 * px_ + i7 * py_ + i8 * pz_;
        float p0 = M[0] * qx + M[1] * qy + M[2] * qz + M[3];
        float p1 = M[4] * qx + M[5] * qy + M[6] * qz + M[7];
        float p2 = M[8] * qx + M[9] * qy + M[10] * qz + M[11];
        float zc = fminf(fmaxf(p2, 1e-5f), 1e5f);
        float sx = p0 / zc, sy = p1 / zc;
        float q0 = A[0] * sx + A[1] * sy + A[2] * zc + A[3];
        float q1 = A[4] * sx + A[5] * sy + A[6] * zc + A[7];
        float row = q1, col = q0;
        int on = (row < (float)IMG_H) && (row >= 0.f) && (col < (float)IMG_W) && (col >= 0.f);
        int ri = (int)row;  // trunc toward zero (matches jnp.trunc->int32)
        int ci = (int)col;
        int minr = ri, maxr = ri, minc = ci, maxc = ci, visv = on;
        for (int off = 4; off >= 1; off >>= 1) {
            minr = min(minr, __shfl_xor(minr, off, 8));
            maxr = max(maxr, __shfl_xor(maxr, off, 8));
            minc = min(minc, __shfl_xor(minc, off, 8));
            maxc = max(maxc, __shfl_xor(maxc, off, 8));
            visv |= __shfl_xor(visv, off, 8);
        }
        if (tid == 0) {
            int x1 = min(max(minc, 0), IMG_W);
            int x2 = min(max(maxc, 0), IMG_W);
            int y1 = min(max(minr, 0), IMG_H);
            int y2 = min(max(maxr, 0), IMG_H);
            float sq = fmaxf((float)max(x2 - x1, y2 - y1), 64.0f);
            s_pw[0] = (float)x1;
            s_pw[1] = (float)y1;
            s_pw[2] = sq;
            s_pw[3] = visv ? 1.0f : 0.0f;
            if (pr == 0) {
                float* pw = ws + WS_PAIR + pair * 4;
                pw[0] = (float)x1; pw[1] = (float)y1; pw[2] = sq;
                pw[3] = visv ? 1.0f : 0.0f;
            }
        }
    }
    __syncthreads();
    if (s_pw[3] == 0.f) return;  // invisible: partials never consumed
    float bx1 = s_pw[0], by1 = s_pw[1], sq = s_pw[2];

    const float* img0 = imgs + (size_t)cam * 3 * IMG_H * IMG_W;
    const float* img1 = img0 + (size_t)(IMG_H * IMG_W);
    const float* img2 = img0 + (size_t)(2 * IMG_H * IMG_W);
    bool active = tid < GRIDN;

    const float ustep = 1.0f / 223.0f;
    float wx0 = 0.f, wx1 = 0.f, mx0 = 0.f, mx1 = 0.f;
    int xi0 = 0, xi1 = 0;
    if (active) {
        float u = (float)tid * ustep;
        float px = bx1 + sq * u;
        float gx = px / (float)IMG_W * 2.0f - 1.0f;
        float ix = ((gx + 1.0f) * (float)IMG_W - 1.0f) / 2.0f;
        float x0f = floorf(ix);
        wx1 = ix - x0f;
        wx0 = 1.0f - wx1;
        float x1f = x0f + 1.0f;
        mx0 = (x0f >= 0.f && x0f <= (float)(IMG_W - 1)) ? 1.f : 0.f;
        mx1 = (x1f >= 0.f && x1f <= (float)(IMG_W - 1)) ? 1.f : 0.f;
        xi0 = min(max((int)x0f, 0), IMG_W - 1);
        xi1 = min(max((int)x1f, 0), IMG_W - 1);
    }

    // register-cached tap values for the two active pixel rows (A=yi0, B=yi1)
    int iyA = -0x40000000, iyB = -0x40000000;
    float vA00 = 0.f, vA01 = 0.f, vA10 = 0.f, vA11 = 0.f, vA20 = 0.f, vA21 = 0.f;
    float vB00 = 0.f, vB01 = 0.f, vB10 = 0.f, vB11 = 0.f, vB20 = 0.f, vB21 = 0.f;

    float acc0 = 0.f, acc1 = 0.f, acc2 = 0.f;
    for (int r = 0; r < 16; ++r) {
        int i = pr * 16 + r;
        float u = (float)i * ustep;
        float py = by1 + sq * u;
        float gy = py / (float)IMG_H * 2.0f - 1.0f;
        float iy = ((gy + 1.0f) * (float)IMG_H - 1.0f) / 2.0f;
        float y0f = floorf(iy);
        float wy1 = iy - y0f;
        float wy0 = 1.0f - wy1;
        float y1f = y0f + 1.0f;
        float my0 = (y0f >= 0.f && y0f <= (float)(IMG_H - 1)) ? 1.f : 0.f;
        float my1 = (y1f >= 0.f && y1f <= (float)(IMG_H - 1)) ? 1.f : 0.f;
        int yi0 = min(max((int)y0f, 0), IMG_H - 1);
        int yi1 = min(max((int)y1f, 0), IMG_H - 1);
        // wave-uniform row-cache update (yi0/yi1 identical across the block)
        if (yi0 != iyA || yi1 != iyB) {
            if (yi0 == iyB) {  // common case: rows advanced by one
                vA00 = vB00; vA01 = vB01; vA10 = vB10; vA11 = vB11; vA20 = vB20; vA21 = vB21;
                iyA = iyB;
            } else if (yi0 != iyA) {
                if (active) {
                    int r0 = yi0 * IMG_W;
                    vA00 = img0[r0 + xi0]; vA01 = img0[r0 + xi1];
                    vA10 = img1[r0 + xi0]; vA11 = img1[r0 + xi1];
                    vA20 = img2[r0 + xi0]; vA21 = img2[r0 + xi1];
                }
                iyA = yi0;
            }
            if (yi1 != iyB) {
                if (active) {
                    int r1 = yi1 * IMG_W;
                    vB00 = img0[r1 + xi0]; vB01 = img0[r1 + xi1];
                    vB10 = img1[r1 + xi0]; vB11 = img1[r1 + xi1];
                    vB20 = img2[r1 + xi0]; vB21 = img2[r1 + xi1];
                }
                iyB = yi1;
            }
        }
        if (active) {
            float w00 = wx0 * wy0, w10 = wx1 * wy0, w01 = wx0 * wy1, w11 = wx1 * wy1;
            float m00 = mx0 * my0, m10 = mx1 * my0, m01 = mx0 * my1, m11 = mx1 * my1;
            acc0 += vA00 * m00 * w00 + vA01 * m10 * w10 + vB00 * m01 * w01 + vB01 * m11 * w11;
            acc1 += vA10 * m00 * w00 + vA11 * m10 * w10 + vB10 * m01 * w01 + vB11 * m11 * w11;
            acc2 += vA20 * m00 * w00 + vA21 * m10 * w10 + vB20 * m01 * w01 + vB21 * m11 * w11;
        }
    }
    // reduce 16 grid-columns -> one pooled cell
    for (int off = 8; off >= 1; off >>= 1) {
        acc0 += __shfl_xor(acc0, off, 16);
        acc1 += __shfl_xor(acc1, off, 16);
        acc2 += __shfl_xor(acc2, off, 16);
    }
    if (active && (tid & 15) == 0) {
        int pj = tid >> 4;
        s_pool[0 * 14 + pj] = acc0 * (1.0f / 256.0f);
        s_pool[1 * 14 + pj] = acc1 * (1.0f / 256.0f);
        s_pool[2 * 14 + pj] = acc2 * (1.0f / 256.0f);
    }
    __syncthreads();

    // ---- fused partial GEMV: 42 pooled values x W rows -> 768 partial dims ----
    float f0 = 0.f, f1 = 0.f, f2 = 0.f;
#pragma unroll
    for (int c = 0; c < 3; ++c) {
        const float* Wc = W + ((size_t)(c * 196 + pr * 14)) * FEATD;
#pragma unroll 14
        for (int pj = 0; pj < 14; ++pj) {
            float p = s_pool[c * 14 + pj];
            const float* wr = Wc + (size_t)pj * FEATD;
            f0 += p * wr[tid];
            f1 += p * wr[tid + 256];
            f2 += p * wr[tid + 512];
        }
    }
    float* po = ws + WS_PART + ((size_t)pair * PROWS + pr) * FEATD;
    po[tid] = f0;
    po[tid + 256] = f1;
    po[tid + 512] = f2;
}

// Sum the 14 partials -> feats; normalize; logits vs text; softmax. One block/pair.
__global__ void __launch_bounds__(256) headred_kernel(const float* __restrict__ text,
                                                      const float* __restrict__ ls_ptr,
                                                      float* __restrict__ ws) {
    int pair = blockIdx.x;
    int tid = threadIdx.x;
    const float* pw = ws + WS_PAIR + pair * 4;
    if (pw[3] == 0.f) {  // invisible: probs = 0 (masked in reference)
        if (tid < NCLASS) ws[WS_PROBS + pair * NCLASS + tid] = 0.f;
        return;
    }
    const float* pb = ws + WS_PART + (size_t)pair * PROWS * FEATD;
    float f0 = 0.f, f1 = 0.f, f2 = 0.f;
    for (int pr = 0; pr < PROWS; ++pr) {
        const float* fp = pb + (size_t)pr * FEATD;
        f0 += fp[tid];
        f1 += fp[tid + 256];
        f2 += fp[tid + 512];
    }
    float pn = f0 * f0 + f1 * f1 + f2 * f2;
    float pl[NCLASS], tq[NCLASS];
    for (int k = 0; k < NCLASS; ++k) {
        const float* tr = text + (size_t)k * FEATD;
        float t0 = tr[tid], t1 = tr[tid + 256], t2 = tr[tid + 512];
        pl[k] = f0 * t0 + f1 * t1 + f2 * t2;
        tq[k] = t0 * t0 + t1 * t1 + t2 * t2;
    }
    for (int off = 32; off >= 1; off >>= 1) {
        pn += __shfl_xor(pn, off);
        for (int k = 0; k < NCLASS; ++k) {
            pl[k] += __shfl_xor(pl[k], off);
            tq[k] += __shfl_xor(tq[k], off);
        }
    }
    __shared__ float rn[4];
    __shared__ float rl[4][NCLASS];
    __shared__ float rq[4][NCLASS];
    int wave = tid >> 6, lane = tid & 63;
    if (lane == 0) {
        rn[wave] = pn;
        for (int k = 0; k < NCLASS; ++k) { rl[wave][k] = pl[k]; rq[wave][k] = tq[k]; }
    }
    __syncthreads();
    if (tid == 0) {
        float n2 = rn[0] + rn[1] + rn[2] + rn[3];
        float nrm = sqrtf(n2);
        float scale = expf(ls_ptr[0]);
        float lg[NCLASS], m = -1e30f;
        for (int k = 0; k < NCLASS; ++k) {
            float d = rl[0][k] + rl[1][k] + rl[2][k] + rl[3][k];
            float tn = sqrtf(rq[0][k] + rq[1][k] + rq[2][k] + rq[3][k]);
            lg[k] = scale * (d / (nrm * tn));
            m = fmaxf(m, lg[k]);
        }
        float s = 0.f;
        for (int k = 0; k < NCLASS; ++k) {
            lg[k] = expf(lg[k] - m);
            s += lg[k];
        }
        float* probs = ws + WS_PROBS + pair * NCLASS;
        for (int k = 0; k < NCLASS; ++k) probs[k] = lg[k] / s;
    }
}

__global__ void finalize_kernel(const int* __restrict__ gt, const float* __restrict__ ws,
                                float* __restrict__ out) {
    int n = threadIdx.x;
    bool match = false;
    if (n < NBOX) {
        const float* probs = ws + WS_PROBS;
        float cnt = 0.f;
        for (int c = 0; c < NCAM; ++c)
            cnt += (ws[WS_PAIR + (c * NBOX + n) * 4 + 3] != 0.f) ? 1.f : 0.f;
        float denom = fmaxf(cnt, 1.0f);
        float mp[NCLASS];
        for (int k = 0; k < NCLASS; ++k) {
            float s = 0.f;
            for (int c = 0; c < NCAM; ++c) s += probs[(c * NBOX + n) * NCLASS + k];
            mp[k] = s / denom;
            out[97 + n * NCLASS + k] = mp[k];
        }
        float best = mp[0];
        int pred = 0;
        for (int k = 1; k < NCLASS; ++k)
            if (mp[k] > best) { best = mp[k]; pred = k; }
        int tr = gt[n] - 1;
        out[n] = (float)pred;
        out[NBOX + n] = (float)tr;
        match = (pred == tr);
    }
    unsigned long long b = __ballot(match);
    if (n == 0) out[2 * NBOX] = (float)__popcll(b) / (float)NBOX;
}

extern "C" void kernel_launch(void* const* d_in, const int* in_sizes, int n_in,
                              void* d_out, int out_size, void* d_ws, size_t ws_size,
                              hipStream_t stream) {
    const float* boxes7 = (const float*)d_in[0];
    const int* gt = (const int*)d_in[1];
    const float* imgs = (const float*)d_in[2];
    const float* l2i = (const float*)d_in[3];
    const float* img_aug = (const float*)d_in[4];
    const float* lidar_aug = (const float*)d_in[5];
    const float* W = (const float*)d_in[6];
    const float* text = (const float*)d_in[7];
    const float* ls = (const float*)d_in[8];
    float* ws = (float*)d_ws;
    float* out = (float*)d_out;

    pool_gemv_kernel<<<NPAIR * PROWS, 256, 0, stream>>>(imgs, boxes7, l2i, img_aug,
                                                        lidar_aug, W, ws);
    headred_kernel<<<NPAIR, 256, 0, stream>>>(text, ls, ws);
    finalize_kernel<<<1, 64, 0, stream>>>(gt, ws, out);
}